// Round 7
// baseline (2250.032 us; speedup 1.0000x reference)
//
#include <hip/hip_runtime.h>
#include <hip/hip_bf16.h>

#define DEV static __device__ __forceinline__

using short8 = __attribute__((ext_vector_type(8))) short;
using f32x4 = __attribute__((ext_vector_type(4))) float;

DEV short f2bf(float f) {
  union { float f; unsigned u; } x; x.f = f;
  unsigned r = x.u + 0x7fffu + ((x.u >> 16) & 1u);
  return (short)(r >> 16);
}

DEV float bf2f(short s) {
  union { unsigned u; float f; } x; x.u = ((unsigned)(unsigned short)s) << 16;
  return x.f;
}

DEV void gload16(const void* g, void* lds) {
  __builtin_amdgcn_global_load_lds(
      (const __attribute__((address_space(1))) void*)g,
      (__attribute__((address_space(3))) void*)lds, 16, 0, 0);
}

// ---------------- merged per-layer weight transpose: f32 [K][N] -> bf16 [N][K]
__global__ __launch_bounds__(256) void transpose_all_k(
    const float* __restrict__ Wqkv, const float* __restrict__ Wo,
    const float* __restrict__ W1, const float* __restrict__ W2,
    short* __restrict__ wqkvT, short* __restrict__ woT,
    short* __restrict__ w1T, short* __restrict__ w2T)
{
  __shared__ short t[64][72];
  const int b = blockIdx.x, tid = threadIdx.x;
  const float* in; short* out; int K, N, tt, nt;
  if (b < 432)       { in = Wqkv; out = wqkvT; K = 768;  N = 2304; tt = b;        nt = 36; }
  else if (b < 576)  { in = Wo;   out = woT;   K = 768;  N = 768;  tt = b - 432;  nt = 12; }
  else if (b < 1152) { in = W1;   out = w1T;   K = 768;  N = 3072; tt = b - 576;  nt = 48; }
  else               { in = W2;   out = w2T;   K = 3072; N = 768;  tt = b - 1152; nt = 12; }
  const int n0 = (tt % nt) * 64, k0 = (tt / nt) * 64;
  #pragma unroll
  for (int p = 0; p < 4; ++p) {
    int r = p * 16 + (tid >> 4), c4 = tid & 15;
    float4 v = *reinterpret_cast<const float4*>(in + (size_t)(k0 + r) * N + n0 + c4 * 4);
    t[r][c4 * 4 + 0] = f2bf(v.x);
    t[r][c4 * 4 + 1] = f2bf(v.y);
    t[r][c4 * 4 + 2] = f2bf(v.z);
    t[r][c4 * 4 + 3] = f2bf(v.w);
  }
  __syncthreads();
  #pragma unroll
  for (int q = 0; q < 2; ++q) {
    int n = tid >> 2, kc = (tid & 3) + q * 4;
    short8 o;
    #pragma unroll
    for (int j = 0; j < 8; ++j) o[j] = t[kc * 8 + j][n];
    *reinterpret_cast<short8*>(out + (size_t)(n0 + n) * K + k0 + kc * 8) = o;
  }
}

// ---------------- pipelined GEMM: C = A[M,K](bf16) @ Bt[N,K]^T (+bias)
// 2-tile LDS dbuf, counted vmcnt(8), raw barriers (T4 counted-vmcnt pattern).
// EPI 0: bias->bf16 (C0); 1: bias+gelu->bf16 (C0); 3: partial bf16, z picks C0/C1
template <int BM, int EPI>
__global__ __launch_bounds__(256) void gemm_bt(
    const short* __restrict__ A, const short* __restrict__ Bt,
    const float* __restrict__ bias,
    void* __restrict__ C0, void* __restrict__ C1,
    int M, int Nn, int Kstride, int Klen)
{
  constexpr int AW = BM / 64;     // A gloads per wave per 32-col subtile
  constexpr int MI = BM / 32;
  constexpr int TA = BM * 64;     // shorts per A k-tile
  __shared__ short As[2 * TA];
  __shared__ short Bs[2 * 128 * 64];
  const int tid = threadIdx.x, lane = tid & 63, w = tid >> 6;
  const int wr = w >> 1, wc = w & 1;
  const int l15 = lane & 15, l4 = lane >> 4;
  const int m0 = blockIdx.y * BM, n0 = blockIdx.x * 128;
  const int koff = blockIdx.z * Klen;
  const int crow = lane >> 2, ccol = (lane & 3) * 8;
  const int nt = Klen >> 6;       // k-tiles of 64 (nt >= 2 at all call sites)

  auto STAGE = [&](int q, int kt) {
    const int k0 = koff + (kt << 6);
    #pragma unroll
    for (int ks = 0; ks < 2; ++ks) {
      #pragma unroll
      for (int s = 0; s < AW; ++s) {
        int c = w * AW + s;
        gload16(A + (size_t)(m0 + c * 16 + crow) * Kstride + k0 + ks * 32 + ccol,
                &As[q * TA + ks * BM * 32 + c * 512]);
      }
      #pragma unroll
      for (int s = 0; s < 2; ++s) {
        int c = w * 2 + s;
        gload16(Bt + (size_t)(n0 + c * 16 + crow) * Kstride + k0 + ks * 32 + ccol,
                &Bs[q * 8192 + ks * 4096 + c * 512]);
      }
    }
  };

  STAGE(0, 0);   // 8 gloads/wave
  STAGE(1, 1);   // 8 more in flight

  f32x4 acc[MI][4] = {};

  for (int kt = 0; kt < nt; ++kt) {
    // wait for tile kt's 8 per-wave loads (oldest); keep tile kt+1's in flight
    if (kt + 1 < nt) asm volatile("s_waitcnt vmcnt(8)" ::: "memory");
    else             asm volatile("s_waitcnt vmcnt(0)" ::: "memory");
    __builtin_amdgcn_s_barrier();        // all waves vmcnt'd -> tile kt fully landed
    __builtin_amdgcn_sched_barrier(0);
    const int q = kt & 1;
    #pragma unroll
    for (int ks = 0; ks < 2; ++ks) {
      short8 af[MI], bfr[4];
      #pragma unroll
      for (int i = 0; i < MI; ++i)
        af[i] = *reinterpret_cast<const short8*>(
            &As[q * TA + ks * BM * 32 + (wr * (BM / 2) + i * 16 + l15) * 32 + l4 * 8]);
      #pragma unroll
      for (int j = 0; j < 4; ++j)
        bfr[j] = *reinterpret_cast<const short8*>(
            &Bs[q * 8192 + ks * 4096 + (wc * 64 + j * 16 + l15) * 32 + l4 * 8]);
      #pragma unroll
      for (int i = 0; i < MI; ++i)
        #pragma unroll
        for (int j = 0; j < 4; ++j)
          acc[i][j] = __builtin_amdgcn_mfma_f32_16x16x32_bf16(af[i], bfr[j], acc[i][j], 0, 0, 0);
    }
    __builtin_amdgcn_sched_barrier(0);   // keep ds_reads above the barrier
    __builtin_amdgcn_s_barrier();        // all waves done reading buf q
    __builtin_amdgcn_sched_barrier(0);
    if (kt + 2 < nt) STAGE(q, kt + 2);   // refill just-freed buffer
  }

  #pragma unroll
  for (int i = 0; i < MI; ++i) {
    #pragma unroll
    for (int j = 0; j < 4; ++j) {
      #pragma unroll
      for (int r = 0; r < 4; ++r) {
        int row = m0 + wr * (BM / 2) + i * 16 + l4 * 4 + r;
        int col = n0 + wc * 64 + j * 16 + l15;
        if constexpr (EPI == 3) {
          short* P = (short*)(blockIdx.z ? C1 : C0);
          P[(size_t)row * Nn + col] = f2bf(acc[i][j][r]);
        } else {
          float v = acc[i][j][r] + bias[col];
          if constexpr (EPI == 1) v = 0.5f * v * (1.0f + erff(v * 0.70710678118654752f));
          ((short*)C0)[(size_t)row * Nn + col] = f2bf(v);
        }
      }
    }
  }
}

// ---------------- Flash attention: qkv[4096][2304] bf16 -> out[4096][768] bf16
__global__ __launch_bounds__(256) void attn_k(
    const short* __restrict__ qkv, const int* __restrict__ amask,
    short* __restrict__ out)
{
  __shared__ short Kl[64][72];
  __shared__ short Vt[64][68];
  __shared__ short Pl[4][16][72];
  const int b = blockIdx.z, h = blockIdx.y, qt = blockIdx.x;
  const int tid = threadIdx.x, lane = tid & 63, w = tid >> 6;
  const int l15 = lane & 15, l4 = lane >> 4;
  const int tok0 = b * 512;
  const int q0 = qt * 64 + w * 16;

  short8 qf[2];
  #pragma unroll
  for (int kk = 0; kk < 2; ++kk)
    qf[kk] = *reinterpret_cast<const short8*>(
        qkv + (size_t)(tok0 + q0 + l15) * 2304 + h * 64 + kk * 32 + l4 * 8);

  f32x4 oacc[4] = {};
  float mrow[4], lrow[4];
  #pragma unroll
  for (int r = 0; r < 4; ++r) { mrow[r] = -1e30f; lrow[r] = 0.f; }

  for (int kt0 = 0; kt0 < 512; kt0 += 64) {
    #pragma unroll
    for (int i = 0; i < 2; ++i) {
      int c = tid + i * 256;
      int r = c >> 3, dc = c & 7;
      short8 v = *reinterpret_cast<const short8*>(
          qkv + (size_t)(tok0 + kt0 + r) * 2304 + 768 + h * 64 + dc * 8);
      *reinterpret_cast<short8*>(&Kl[r][dc * 8]) = v;
    }
    #pragma unroll
    for (int i = 0; i < 2; ++i) {
      int c = tid + i * 256;
      int r = c >> 3, dc = c & 7;
      short8 v = *reinterpret_cast<const short8*>(
          qkv + (size_t)(tok0 + kt0 + r) * 2304 + 1536 + h * 64 + dc * 8);
      #pragma unroll
      for (int j = 0; j < 8; ++j) Vt[dc * 8 + j][r] = v[j];
    }
    __syncthreads();

    f32x4 sacc[4] = {};
    #pragma unroll
    for (int t = 0; t < 4; ++t) {
      #pragma unroll
      for (int kk = 0; kk < 2; ++kk) {
        short8 kf = *reinterpret_cast<const short8*>(&Kl[t * 16 + l15][kk * 32 + l4 * 8]);
        sacc[t] = __builtin_amdgcn_mfma_f32_16x16x32_bf16(qf[kk], kf, sacc[t], 0, 0, 0);
      }
    }
    float p[4][4];
    #pragma unroll
    for (int t = 0; t < 4; ++t) {
      int ktok = kt0 + t * 16 + l15;
      float biasv = amask[b * 512 + ktok] ? 0.f : -1e9f;
      #pragma unroll
      for (int r = 0; r < 4; ++r) p[t][r] = sacc[t][r] * 0.125f + biasv;
    }
    #pragma unroll
    for (int r = 0; r < 4; ++r) {
      float mx = fmaxf(fmaxf(p[0][r], p[1][r]), fmaxf(p[2][r], p[3][r]));
      #pragma unroll
      for (int s = 1; s <= 8; s <<= 1) mx = fmaxf(mx, __shfl_xor(mx, s, 64));
      float mnew = fmaxf(mrow[r], mx);
      float alpha = __expf(mrow[r] - mnew);
      mrow[r] = mnew;
      float sum = 0.f;
      #pragma unroll
      for (int t = 0; t < 4; ++t) { p[t][r] = __expf(p[t][r] - mnew); sum += p[t][r]; }
      #pragma unroll
      for (int s = 1; s <= 8; s <<= 1) sum += __shfl_xor(sum, s, 64);
      lrow[r] = lrow[r] * alpha + sum;
      #pragma unroll
      for (int t = 0; t < 4; ++t) oacc[t][r] *= alpha;
    }
    #pragma unroll
    for (int t = 0; t < 4; ++t)
      #pragma unroll
      for (int r = 0; r < 4; ++r)
        Pl[w][l4 * 4 + r][t * 16 + l15] = f2bf(p[t][r]);
    __syncthreads();
    #pragma unroll
    for (int kk = 0; kk < 2; ++kk) {
      short8 pf = *reinterpret_cast<const short8*>(&Pl[w][l15][kk * 32 + l4 * 8]);
      #pragma unroll
      for (int t = 0; t < 4; ++t) {
        const unsigned* vp = reinterpret_cast<const unsigned*>(&Vt[t * 16 + l15][0]);
        union { short8 s; unsigned u[4]; } vu;
        #pragma unroll
        for (int w2 = 0; w2 < 4; ++w2) vu.u[w2] = vp[kk * 16 + l4 * 4 + w2];
        oacc[t] = __builtin_amdgcn_mfma_f32_16x16x32_bf16(pf, vu.s, oacc[t], 0, 0, 0);
      }
    }
    __syncthreads();
  }

  #pragma unroll
  for (int t = 0; t < 4; ++t)
    #pragma unroll
    for (int r = 0; r < 4; ++r) {
      int tok = tok0 + q0 + l4 * 4 + r;
      int dh = t * 16 + l15;
      out[(size_t)tok * 768 + h * 64 + dh] = f2bf(oacc[t][r] / lrow[r]);
    }
}

// ---------------- LN of (p0 + p1 + bias + resid): bf16 partials -> f32 + bf16 out
__global__ __launch_bounds__(256) void ln2_k(
    const short* __restrict__ p0, const short* __restrict__ p1,
    const float* __restrict__ bias, const float* __restrict__ resid,
    const float* __restrict__ g, const float* __restrict__ be,
    float* __restrict__ xf, short* __restrict__ xb)
{
  const int t = blockIdx.x, tid = threadIdx.x;
  const size_t base = (size_t)t * 768;
  float v[3], s = 0.f, ss = 0.f;
  #pragma unroll
  for (int i = 0; i < 3; ++i) {
    int c = tid + i * 256;
    v[i] = bf2f(p0[base + c]) + bf2f(p1[base + c]) + bias[c] + resid[base + c];
    s += v[i]; ss += v[i] * v[i];
  }
  __shared__ float red[4][2];
  #pragma unroll
  for (int m = 1; m <= 32; m <<= 1) { s += __shfl_xor(s, m, 64); ss += __shfl_xor(ss, m, 64); }
  int w = tid >> 6;
  if ((tid & 63) == 0) { red[w][0] = s; red[w][1] = ss; }
  __syncthreads();
  s = red[0][0] + red[1][0] + red[2][0] + red[3][0];
  ss = red[0][1] + red[1][1] + red[2][1] + red[3][1];
  float mean = s * (1.f / 768.f);
  float var = ss * (1.f / 768.f) - mean * mean;
  float rs = rsqrtf(var + 1e-12f);
  #pragma unroll
  for (int i = 0; i < 3; ++i) {
    int c = tid + i * 256;
    float o = (v[i] - mean) * rs * g[c] + be[c];
    xf[base + c] = o;
    xb[base + c] = f2bf(o);
  }
}

// ---------------- embedding + LN
__global__ __launch_bounds__(256) void embed_ln_k(
    const int* __restrict__ ids, const float* __restrict__ tok_emb,
    const float* __restrict__ pos_emb, const float* __restrict__ g,
    const float* __restrict__ be, float* __restrict__ xf, short* __restrict__ xb)
{
  const int t = blockIdx.x, tid = threadIdx.x;
  const int id = ids[t], sp = t & 511;
  float v[3], s = 0.f, ss = 0.f;
  #pragma unroll
  for (int i = 0; i < 3; ++i) {
    int c = tid + i * 256;
    v[i] = tok_emb[(size_t)id * 768 + c] + pos_emb[(size_t)sp * 768 + c];
    s += v[i]; ss += v[i] * v[i];
  }
  __shared__ float red[4][2];
  #pragma unroll
  for (int m = 1; m <= 32; m <<= 1) { s += __shfl_xor(s, m, 64); ss += __shfl_xor(ss, m, 64); }
  int w = tid >> 6;
  if ((tid & 63) == 0) { red[w][0] = s; red[w][1] = ss; }
  __syncthreads();
  s = red[0][0] + red[1][0] + red[2][0] + red[3][0];
  ss = red[0][1] + red[1][1] + red[2][1] + red[3][1];
  float mean = s * (1.f / 768.f);
  float var = ss * (1.f / 768.f) - mean * mean;
  float rs = rsqrtf(var + 1e-12f);
  #pragma unroll
  for (int i = 0; i < 3; ++i) {
    int c = tid + i * 256;
    float o = (v[i] - mean) * rs * g[c] + be[c];
    xf[(size_t)t * 768 + c] = o;
    xb[(size_t)t * 768 + c] = f2bf(o);
  }
}

// ---------------- gather/scatter (parallel): cls + sentinel rows -> out[8][64][768]
__global__ __launch_bounds__(512) void gather_k(
    const int* __restrict__ ids, const float* __restrict__ x, float* __restrict__ out)
{
  const int doc = blockIdx.x, tid = threadIdx.x;
  const int lane = tid & 63, w = tid >> 6;
  __shared__ int src[64];
  __shared__ int wave_sent[8];
  __shared__ int cls_pos;
  if (tid < 64) src[tid] = -1;
  if (tid == 0) cls_pos = 0x7fffffff;
  __syncthreads();

  const int id = ids[doc * 512 + tid];
  const bool is_sent = (id == 103);
  const unsigned long long m = __ballot(is_sent);
  if (lane == 0) wave_sent[w] = __popcll(m);
  if (id == 102) atomicMin(&cls_pos, tid);
  __syncthreads();

  int total = 0, prefix = 0;
  #pragma unroll
  for (int i = 0; i < 8; ++i) {
    int c = wave_sent[i];
    if (i < w) prefix += c;
    total += c;
  }
  if (is_sent) {
    unsigned long long lt = lane ? (~0ULL >> (64 - lane)) : 0ULL;
    int d = 1 + prefix + __popcll(m & lt);
    if (d < total && d < 64) src[d] = tid;
  }
  if (tid == 0 && total > 0 && cls_pos != 0x7fffffff) src[0] = cls_pos;
  __syncthreads();

  for (int i = tid; i < 64 * 192; i += 512) {
    int row = i / 192, c4 = i - row * 192;
    int sp = src[row];
    float4 v = make_float4(0.f, 0.f, 0.f, 0.f);
    if (sp >= 0)
      v = reinterpret_cast<const float4*>(x + (size_t)(doc * 512 + sp) * 768)[c4];
    reinterpret_cast<float4*>(out + (size_t)doc * 64 * 768)[i] = v;
  }
}

extern "C" void kernel_launch(void* const* d_in, const int* in_sizes, int n_in,
                              void* d_out, int out_size, void* d_ws, size_t ws_size,
                              hipStream_t stream)
{
  const int* ids = (const int*)d_in[0];
  const int* am = (const int*)d_in[1];
  const float* tok_emb = (const float*)d_in[2];
  const float* pos_emb = (const float*)d_in[3];
  const float* eg = (const float*)d_in[4];
  const float* eb = (const float*)d_in[5];
  const float* Wqkv = (const float*)d_in[6];
  const float* bqkv = (const float*)d_in[7];
  const float* Wo = (const float*)d_in[8];
  const float* bo = (const float*)d_in[9];
  const float* g1 = (const float*)d_in[10];
  const float* b1n = (const float*)d_in[11];
  const float* W1 = (const float*)d_in[12];
  const float* b1f = (const float*)d_in[13];
  const float* W2 = (const float*)d_in[14];
  const float* b2f = (const float*)d_in[15];
  const float* g2 = (const float*)d_in[16];
  const float* b2n = (const float*)d_in[17];

  char* ws = (char*)d_ws;
  float* x_f   = (float*)(ws);                  // residual stream (f32)
  short* x_b   = (short*)(ws + 12582912);       // residual (bf16)
  float* x2_f  = (float*)(ws + 18874368);       // post-LN1 (f32)
  short* x2_b  = (short*)(ws + 31457280);       // post-LN1 (bf16)
  short* skp0  = (short*)(ws + 37748736);       // split-K partial 0 (bf16)
  short* qkv   = (short*)(ws + 50331648);       // QKV (bf16)
  short* skp1b = (short*)(ws + 50331648);       // FFN2 partial 1 (aliases dead qkv)
  short* attn  = (short*)(ws + 69206016);       // attn out (bf16)
  short* hb    = (short*)(ws + 75497472);       // FFN1 out (bf16)
  short* skp1a = (short*)(ws + 75497472);       // O-proj partial 1 (aliases dead hb)
  short* wqkvT = (short*)(ws + 100663296);
  short* woT   = (short*)(ws + 104202240);
  short* w1T   = (short*)(ws + 105381888);
  short* w2T   = (short*)(ws + 110100480);      // end ~109.5 MB

  embed_ln_k<<<4096, 256, 0, stream>>>(ids, tok_emb, pos_emb, eg, eb, x_f, x_b);

  for (int l = 0; l < 12; ++l) {
    transpose_all_k<<<1728, 256, 0, stream>>>(
        Wqkv + (size_t)l * 768 * 2304, Wo + (size_t)l * 768 * 768,
        W1 + (size_t)l * 768 * 3072, W2 + (size_t)l * 3072 * 768,
        wqkvT, woT, w1T, w2T);

    gemm_bt<128, 0><<<dim3(18, 32, 1), 256, 0, stream>>>(
        x_b, wqkvT, bqkv + (size_t)l * 2304, qkv, nullptr, 4096, 2304, 768, 768);
    attn_k<<<dim3(8, 12, 8), 256, 0, stream>>>(qkv, am, attn);

    gemm_bt<128, 3><<<dim3(6, 32, 2), 256, 0, stream>>>(
        attn, woT, nullptr, skp0, skp1a, 4096, 768, 768, 384);
    ln2_k<<<4096, 256, 0, stream>>>(
        skp0, skp1a, bo + (size_t)l * 768, x_f,
        g1 + (size_t)l * 768, b1n + (size_t)l * 768, x2_f, x2_b);

    gemm_bt<128, 1><<<dim3(24, 32, 1), 256, 0, stream>>>(
        x2_b, w1T, b1f + (size_t)l * 3072, hb, nullptr, 4096, 3072, 768, 768);

    gemm_bt<128, 3><<<dim3(6, 32, 2), 256, 0, stream>>>(
        hb, w2T, nullptr, skp0, skp1b, 4096, 768, 3072, 1536);
    ln2_k<<<4096, 256, 0, stream>>>(
        skp0, skp1b, b2f + (size_t)l * 768, x2_f,
        g2 + (size_t)l * 768, b2n + (size_t)l * 768, x_f, x_b);
  }

  gather_k<<<8, 512, 0, stream>>>(ids, x_f, (float*)d_out);
}

// Round 8
// 2208.058 us; speedup vs baseline: 1.0190x; 1.0190x over previous
//
#include <hip/hip_runtime.h>
#include <hip/hip_bf16.h>

#define DEV static __device__ __forceinline__

using short8 = __attribute__((ext_vector_type(8))) short;
using f32x4 = __attribute__((ext_vector_type(4))) float;

DEV short f2bf(float f) {
  union { float f; unsigned u; } x; x.f = f;
  unsigned r = x.u + 0x7fffu + ((x.u >> 16) & 1u);
  return (short)(r >> 16);
}

DEV float bf2f(short s) {
  union { unsigned u; float f; } x; x.u = ((unsigned)(unsigned short)s) << 16;
  return x.f;
}

DEV void gload16(const void* g, void* lds) {
  __builtin_amdgcn_global_load_lds(
      (const __attribute__((address_space(1))) void*)g,
      (__attribute__((address_space(3))) void*)lds, 16, 0, 0);
}

// ---------------- merged per-layer weight transpose: f32 [K][N] -> bf16 [N][K]
__global__ __launch_bounds__(256) void transpose_all_k(
    const float* __restrict__ Wqkv, const float* __restrict__ Wo,
    const float* __restrict__ W1, const float* __restrict__ W2,
    short* __restrict__ wqkvT, short* __restrict__ woT,
    short* __restrict__ w1T, short* __restrict__ w2T)
{
  __shared__ short t[64][72];
  const int b = blockIdx.x, tid = threadIdx.x;
  const float* in; short* out; int K, N, tt, nt;
  if (b < 432)       { in = Wqkv; out = wqkvT; K = 768;  N = 2304; tt = b;        nt = 36; }
  else if (b < 576)  { in = Wo;   out = woT;   K = 768;  N = 768;  tt = b - 432;  nt = 12; }
  else if (b < 1152) { in = W1;   out = w1T;   K = 768;  N = 3072; tt = b - 576;  nt = 48; }
  else               { in = W2;   out = w2T;   K = 3072; N = 768;  tt = b - 1152; nt = 12; }
  const int n0 = (tt % nt) * 64, k0 = (tt / nt) * 64;
  #pragma unroll
  for (int p = 0; p < 4; ++p) {
    int r = p * 16 + (tid >> 4), c4 = tid & 15;
    float4 v = *reinterpret_cast<const float4*>(in + (size_t)(k0 + r) * N + n0 + c4 * 4);
    t[r][c4 * 4 + 0] = f2bf(v.x);
    t[r][c4 * 4 + 1] = f2bf(v.y);
    t[r][c4 * 4 + 2] = f2bf(v.z);
    t[r][c4 * 4 + 3] = f2bf(v.w);
  }
  __syncthreads();
  #pragma unroll
  for (int q = 0; q < 2; ++q) {
    int n = tid >> 2, kc = (tid & 3) + q * 4;
    short8 o;
    #pragma unroll
    for (int j = 0; j < 8; ++j) o[j] = t[kc * 8 + j][n];
    *reinterpret_cast<short8*>(out + (size_t)(n0 + n) * K + k0 + kc * 8) = o;
  }
}

// ---------------- GEMM (round-6 proven structure, BK=64 as 2x32 subtiles):
// C = A[M,K](bf16) @ Bt[N,K]^T + bias. EPI 0: bias->bf16; 1: bias+gelu->bf16
template <int BM, int EPI>
__global__ __launch_bounds__(256) void gemm_bt(
    const short* __restrict__ A, const short* __restrict__ Bt,
    const float* __restrict__ bias, const float* __restrict__ resid,
    void* __restrict__ Cout, int M, int Nn, int K)
{
  constexpr int AW = BM / 64;
  constexpr int MI = BM / 32;
  __shared__ short As[2 * BM * 32];
  __shared__ short Bs[2 * 128 * 32];
  const int tid = threadIdx.x, lane = tid & 63, w = tid >> 6;
  const int wr = w >> 1, wc = w & 1;
  const int l15 = lane & 15, l4 = lane >> 4;
  const int m0 = blockIdx.y * BM, n0 = blockIdx.x * 128;
  const int crow = lane >> 2, ccol = (lane & 3) * 8;

  f32x4 acc[MI][4] = {};

  for (int k0 = 0; k0 < K; k0 += 64) {
    #pragma unroll
    for (int ks = 0; ks < 2; ++ks) {
      #pragma unroll
      for (int s = 0; s < AW; ++s) {
        int c = w * AW + s;
        gload16(A + (size_t)(m0 + c * 16 + crow) * K + k0 + ks * 32 + ccol,
                &As[ks * BM * 32 + c * 512]);
      }
      #pragma unroll
      for (int s = 0; s < 2; ++s) {
        int c = w * 2 + s;
        gload16(Bt + (size_t)(n0 + c * 16 + crow) * K + k0 + ks * 32 + ccol,
                &Bs[ks * 128 * 32 + c * 512]);
      }
    }
    __syncthreads();

    #pragma unroll
    for (int ks = 0; ks < 2; ++ks) {
      short8 af[MI], bfr[4];
      #pragma unroll
      for (int i = 0; i < MI; ++i)
        af[i] = *reinterpret_cast<const short8*>(
            &As[ks * BM * 32 + (wr * (BM / 2) + i * 16 + l15) * 32 + l4 * 8]);
      #pragma unroll
      for (int j = 0; j < 4; ++j)
        bfr[j] = *reinterpret_cast<const short8*>(
            &Bs[ks * 128 * 32 + (wc * 64 + j * 16 + l15) * 32 + l4 * 8]);
      #pragma unroll
      for (int i = 0; i < MI; ++i)
        #pragma unroll
        for (int j = 0; j < 4; ++j)
          acc[i][j] = __builtin_amdgcn_mfma_f32_16x16x32_bf16(af[i], bfr[j], acc[i][j], 0, 0, 0);
    }
    __syncthreads();
  }

  #pragma unroll
  for (int i = 0; i < MI; ++i) {
    #pragma unroll
    for (int j = 0; j < 4; ++j) {
      #pragma unroll
      for (int r = 0; r < 4; ++r) {
        int row = m0 + wr * (BM / 2) + i * 16 + l4 * 4 + r;
        int col = n0 + wc * 64 + j * 16 + l15;
        float v = acc[i][j][r] + bias[col];
        if constexpr (EPI == 1) v = 0.5f * v * (1.0f + erff(v * 0.70710678118654752f));
        ((short*)Cout)[(size_t)row * Nn + col] = f2bf(v);
      }
    }
  }
}

// ---------------- split-K GEMM (BK=64, 4-way): bf16 partials, z in {0..3}
__global__ __launch_bounds__(256) void gemm_sk(
    const short* __restrict__ A, const short* __restrict__ Bt,
    short* __restrict__ p0, short* __restrict__ p1,
    short* __restrict__ p2, short* __restrict__ p3,
    int M, int Nn, int Kstride, int Klen)
{
  __shared__ short As[2 * 128 * 32];
  __shared__ short Bs[2 * 128 * 32];
  const int tid = threadIdx.x, lane = tid & 63, w = tid >> 6;
  const int wr = w >> 1, wc = w & 1;
  const int l15 = lane & 15, l4 = lane >> 4;
  const int m0 = blockIdx.y * 128, n0 = blockIdx.x * 128;
  const int koff = blockIdx.z * Klen;
  const int crow = lane >> 2, ccol = (lane & 3) * 8;

  f32x4 acc[4][4] = {};

  for (int k0 = 0; k0 < Klen; k0 += 64) {
    #pragma unroll
    for (int ks = 0; ks < 2; ++ks) {
      #pragma unroll
      for (int s = 0; s < 2; ++s) {
        int c = w * 2 + s;
        gload16(A + (size_t)(m0 + c * 16 + crow) * Kstride + koff + k0 + ks * 32 + ccol,
                &As[ks * 4096 + c * 512]);
      }
      #pragma unroll
      for (int s = 0; s < 2; ++s) {
        int c = w * 2 + s;
        gload16(Bt + (size_t)(n0 + c * 16 + crow) * Kstride + koff + k0 + ks * 32 + ccol,
                &Bs[ks * 4096 + c * 512]);
      }
    }
    __syncthreads();

    #pragma unroll
    for (int ks = 0; ks < 2; ++ks) {
      short8 af[4], bfr[4];
      #pragma unroll
      for (int i = 0; i < 4; ++i)
        af[i] = *reinterpret_cast<const short8*>(
            &As[ks * 4096 + (wr * 64 + i * 16 + l15) * 32 + l4 * 8]);
      #pragma unroll
      for (int j = 0; j < 4; ++j)
        bfr[j] = *reinterpret_cast<const short8*>(
            &Bs[ks * 4096 + (wc * 64 + j * 16 + l15) * 32 + l4 * 8]);
      #pragma unroll
      for (int i = 0; i < 4; ++i)
        #pragma unroll
        for (int j = 0; j < 4; ++j)
          acc[i][j] = __builtin_amdgcn_mfma_f32_16x16x32_bf16(af[i], bfr[j], acc[i][j], 0, 0, 0);
    }
    __syncthreads();
  }

  short* P = (blockIdx.z == 0) ? p0 : (blockIdx.z == 1) ? p1 : (blockIdx.z == 2) ? p2 : p3;
  #pragma unroll
  for (int i = 0; i < 4; ++i)
    #pragma unroll
    for (int j = 0; j < 4; ++j)
      #pragma unroll
      for (int r = 0; r < 4; ++r) {
        int row = m0 + wr * 64 + i * 16 + l4 * 4 + r;
        int col = n0 + wc * 64 + j * 16 + l15;
        P[(size_t)row * Nn + col] = f2bf(acc[i][j][r]);
      }
}

// ---------------- Flash attention: qkv[4096][2304] bf16 -> out[4096][768] bf16
__global__ __launch_bounds__(256) void attn_k(
    const short* __restrict__ qkv, const int* __restrict__ amask,
    short* __restrict__ out)
{
  __shared__ short Kl[64][72];
  __shared__ short Vt[64][68];
  __shared__ short Pl[4][16][72];
  const int b = blockIdx.z, h = blockIdx.y, qt = blockIdx.x;
  const int tid = threadIdx.x, lane = tid & 63, w = tid >> 6;
  const int l15 = lane & 15, l4 = lane >> 4;
  const int tok0 = b * 512;
  const int q0 = qt * 64 + w * 16;

  short8 qf[2];
  #pragma unroll
  for (int kk = 0; kk < 2; ++kk)
    qf[kk] = *reinterpret_cast<const short8*>(
        qkv + (size_t)(tok0 + q0 + l15) * 2304 + h * 64 + kk * 32 + l4 * 8);

  f32x4 oacc[4] = {};
  float mrow[4], lrow[4];
  #pragma unroll
  for (int r = 0; r < 4; ++r) { mrow[r] = -1e30f; lrow[r] = 0.f; }

  for (int kt0 = 0; kt0 < 512; kt0 += 64) {
    #pragma unroll
    for (int i = 0; i < 2; ++i) {
      int c = tid + i * 256;
      int r = c >> 3, dc = c & 7;
      short8 v = *reinterpret_cast<const short8*>(
          qkv + (size_t)(tok0 + kt0 + r) * 2304 + 768 + h * 64 + dc * 8);
      *reinterpret_cast<short8*>(&Kl[r][dc * 8]) = v;
    }
    #pragma unroll
    for (int i = 0; i < 2; ++i) {
      int c = tid + i * 256;
      int r = c >> 3, dc = c & 7;
      short8 v = *reinterpret_cast<const short8*>(
          qkv + (size_t)(tok0 + kt0 + r) * 2304 + 1536 + h * 64 + dc * 8);
      #pragma unroll
      for (int j = 0; j < 8; ++j) Vt[dc * 8 + j][r] = v[j];
    }
    __syncthreads();

    f32x4 sacc[4] = {};
    #pragma unroll
    for (int t = 0; t < 4; ++t) {
      #pragma unroll
      for (int kk = 0; kk < 2; ++kk) {
        short8 kf = *reinterpret_cast<const short8*>(&Kl[t * 16 + l15][kk * 32 + l4 * 8]);
        sacc[t] = __builtin_amdgcn_mfma_f32_16x16x32_bf16(qf[kk], kf, sacc[t], 0, 0, 0);
      }
    }
    float p[4][4];
    #pragma unroll
    for (int t = 0; t < 4; ++t) {
      int ktok = kt0 + t * 16 + l15;
      float biasv = amask[b * 512 + ktok] ? 0.f : -1e9f;
      #pragma unroll
      for (int r = 0; r < 4; ++r) p[t][r] = sacc[t][r] * 0.125f + biasv;
    }
    #pragma unroll
    for (int r = 0; r < 4; ++r) {
      float mx = fmaxf(fmaxf(p[0][r], p[1][r]), fmaxf(p[2][r], p[3][r]));
      #pragma unroll
      for (int s = 1; s <= 8; s <<= 1) mx = fmaxf(mx, __shfl_xor(mx, s, 64));
      float mnew = fmaxf(mrow[r], mx);
      float alpha = __expf(mrow[r] - mnew);
      mrow[r] = mnew;
      float sum = 0.f;
      #pragma unroll
      for (int t = 0; t < 4; ++t) { p[t][r] = __expf(p[t][r] - mnew); sum += p[t][r]; }
      #pragma unroll
      for (int s = 1; s <= 8; s <<= 1) sum += __shfl_xor(sum, s, 64);
      lrow[r] = lrow[r] * alpha + sum;
      #pragma unroll
      for (int t = 0; t < 4; ++t) oacc[t][r] *= alpha;
    }
    // P -> per-wave LDS (wave-private: no cross-wave barrier needed;
    // compiler inserts the wave-local lgkmcnt before the dependent read)
    #pragma unroll
    for (int t = 0; t < 4; ++t)
      #pragma unroll
      for (int r = 0; r < 4; ++r)
        Pl[w][l4 * 4 + r][t * 16 + l15] = f2bf(p[t][r]);
    #pragma unroll
    for (int kk = 0; kk < 2; ++kk) {
      short8 pf = *reinterpret_cast<const short8*>(&Pl[w][l15][kk * 32 + l4 * 8]);
      #pragma unroll
      for (int t = 0; t < 4; ++t) {
        const unsigned* vp = reinterpret_cast<const unsigned*>(&Vt[t * 16 + l15][0]);
        union { short8 s; unsigned u[4]; } vu;
        #pragma unroll
        for (int w2 = 0; w2 < 4; ++w2) vu.u[w2] = vp[kk * 16 + l4 * 4 + w2];
        oacc[t] = __builtin_amdgcn_mfma_f32_16x16x32_bf16(pf, vu.s, oacc[t], 0, 0, 0);
      }
    }
    __syncthreads();
  }

  #pragma unroll
  for (int t = 0; t < 4; ++t)
    #pragma unroll
    for (int r = 0; r < 4; ++r) {
      int tok = tok0 + q0 + l4 * 4 + r;
      int dh = t * 16 + l15;
      out[(size_t)tok * 768 + h * 64 + dh] = f2bf(oacc[t][r] / lrow[r]);
    }
}

// ---------------- LN of (p0+p1+p2+p3 + bias + resid): bf16 partials -> f32 + bf16 out
__global__ __launch_bounds__(256) void ln2_k(
    const short* __restrict__ p0, const short* __restrict__ p1,
    const short* __restrict__ p2, const short* __restrict__ p3,
    const float* __restrict__ bias, const float* __restrict__ resid,
    const float* __restrict__ g, const float* __restrict__ be,
    float* __restrict__ xf, short* __restrict__ xb)
{
  const int t = blockIdx.x, tid = threadIdx.x;
  const size_t base = (size_t)t * 768;
  float v[3], s = 0.f, ss = 0.f;
  #pragma unroll
  for (int i = 0; i < 3; ++i) {
    int c = tid + i * 256;
    v[i] = (bf2f(p0[base + c]) + bf2f(p1[base + c]))
         + (bf2f(p2[base + c]) + bf2f(p3[base + c]))
         + bias[c] + resid[base + c];
    s += v[i]; ss += v[i] * v[i];
  }
  __shared__ float red[4][2];
  #pragma unroll
  for (int m = 1; m <= 32; m <<= 1) { s += __shfl_xor(s, m, 64); ss += __shfl_xor(ss, m, 64); }
  int w = tid >> 6;
  if ((tid & 63) == 0) { red[w][0] = s; red[w][1] = ss; }
  __syncthreads();
  s = red[0][0] + red[1][0] + red[2][0] + red[3][0];
  ss = red[0][1] + red[1][1] + red[2][1] + red[3][1];
  float mean = s * (1.f / 768.f);
  float var = ss * (1.f / 768.f) - mean * mean;
  float rs = rsqrtf(var + 1e-12f);
  #pragma unroll
  for (int i = 0; i < 3; ++i) {
    int c = tid + i * 256;
    float o = (v[i] - mean) * rs * g[c] + be[c];
    xf[base + c] = o;
    xb[base + c] = f2bf(o);
  }
}

// ---------------- embedding + LN
__global__ __launch_bounds__(256) void embed_ln_k(
    const int* __restrict__ ids, const float* __restrict__ tok_emb,
    const float* __restrict__ pos_emb, const float* __restrict__ g,
    const float* __restrict__ be, float* __restrict__ xf, short* __restrict__ xb)
{
  const int t = blockIdx.x, tid = threadIdx.x;
  const int id = ids[t], sp = t & 511;
  float v[3], s = 0.f, ss = 0.f;
  #pragma unroll
  for (int i = 0; i < 3; ++i) {
    int c = tid + i * 256;
    v[i] = tok_emb[(size_t)id * 768 + c] + pos_emb[(size_t)sp * 768 + c];
    s += v[i]; ss += v[i] * v[i];
  }
  __shared__ float red[4][2];
  #pragma unroll
  for (int m = 1; m <= 32; m <<= 1) { s += __shfl_xor(s, m, 64); ss += __shfl_xor(ss, m, 64); }
  int w = tid >> 6;
  if ((tid & 63) == 0) { red[w][0] = s; red[w][1] = ss; }
  __syncthreads();
  s = red[0][0] + red[1][0] + red[2][0] + red[3][0];
  ss = red[0][1] + red[1][1] + red[2][1] + red[3][1];
  float mean = s * (1.f / 768.f);
  float var = ss * (1.f / 768.f) - mean * mean;
  float rs = rsqrtf(var + 1e-12f);
  #pragma unroll
  for (int i = 0; i < 3; ++i) {
    int c = tid + i * 256;
    float o = (v[i] - mean) * rs * g[c] + be[c];
    xf[(size_t)t * 768 + c] = o;
    xb[(size_t)t * 768 + c] = f2bf(o);
  }
}

// ---------------- gather/scatter (parallel): cls + sentinel rows -> out[8][64][768]
__global__ __launch_bounds__(512) void gather_k(
    const int* __restrict__ ids, const float* __restrict__ x, float* __restrict__ out)
{
  const int doc = blockIdx.x, tid = threadIdx.x;
  const int lane = tid & 63, w = tid >> 6;
  __shared__ int src[64];
  __shared__ int wave_sent[8];
  __shared__ int cls_pos;
  if (tid < 64) src[tid] = -1;
  if (tid == 0) cls_pos = 0x7fffffff;
  __syncthreads();

  const int id = ids[doc * 512 + tid];
  const bool is_sent = (id == 103);
  const unsigned long long m = __ballot(is_sent);
  if (lane == 0) wave_sent[w] = __popcll(m);
  if (id == 102) atomicMin(&cls_pos, tid);
  __syncthreads();

  int total = 0, prefix = 0;
  #pragma unroll
  for (int i = 0; i < 8; ++i) {
    int c = wave_sent[i];
    if (i < w) prefix += c;
    total += c;
  }
  if (is_sent) {
    unsigned long long lt = lane ? (~0ULL >> (64 - lane)) : 0ULL;
    int d = 1 + prefix + __popcll(m & lt);
    if (d < total && d < 64) src[d] = tid;
  }
  if (tid == 0 && total > 0 && cls_pos != 0x7fffffff) src[0] = cls_pos;
  __syncthreads();

  for (int i = tid; i < 64 * 192; i += 512) {
    int row = i / 192, c4 = i - row * 192;
    int sp = src[row];
    float4 v = make_float4(0.f, 0.f, 0.f, 0.f);
    if (sp >= 0)
      v = reinterpret_cast<const float4*>(x + (size_t)(doc * 512 + sp) * 768)[c4];
    reinterpret_cast<float4*>(out + (size_t)doc * 64 * 768)[i] = v;
  }
}

extern "C" void kernel_launch(void* const* d_in, const int* in_sizes, int n_in,
                              void* d_out, int out_size, void* d_ws, size_t ws_size,
                              hipStream_t stream)
{
  const int* ids = (const int*)d_in[0];
  const int* am = (const int*)d_in[1];
  const float* tok_emb = (const float*)d_in[2];
  const float* pos_emb = (const float*)d_in[3];
  const float* eg = (const float*)d_in[4];
  const float* eb = (const float*)d_in[5];
  const float* Wqkv = (const float*)d_in[6];
  const float* bqkv = (const float*)d_in[7];
  const float* Wo = (const float*)d_in[8];
  const float* bo = (const float*)d_in[9];
  const float* g1 = (const float*)d_in[10];
  const float* b1n = (const float*)d_in[11];
  const float* W1 = (const float*)d_in[12];
  const float* b1f = (const float*)d_in[13];
  const float* W2 = (const float*)d_in[14];
  const float* b2f = (const float*)d_in[15];
  const float* g2 = (const float*)d_in[16];
  const float* b2n = (const float*)d_in[17];

  char* ws = (char*)d_ws;
  float* x_f   = (float*)(ws);                  // residual stream (f32)
  short* x_b   = (short*)(ws + 12582912);       // residual (bf16)
  float* x2_f  = (float*)(ws + 18874368);       // post-LN1 (f32)
  short* x2_b  = (short*)(ws + 31457280);       // post-LN1 (bf16)
  short* pp0   = (short*)(ws + 37748736);       // split-K partial 0 (bf16, 6.29MB)
  short* pp1   = (short*)(ws + 37748736 + 6291456);  // partial 1
  short* qkv   = (short*)(ws + 50331648);       // QKV (bf16, 18.9MB)
  short* pp2   = (short*)(ws + 50331648);       // partial 2 (aliases dead qkv)
  short* pp3   = (short*)(ws + 50331648 + 6291456);  // partial 3
  short* attn  = (short*)(ws + 69206016);       // attn out (bf16)
  short* hb    = (short*)(ws + 75497472);       // FFN1 out (bf16, 25MB)
  short* wqkvT = (short*)(ws + 100663296);
  short* woT   = (short*)(ws + 104202240);
  short* w1T   = (short*)(ws + 105381888);
  short* w2T   = (short*)(ws + 110100480);      // end ~109.5 MB

  embed_ln_k<<<4096, 256, 0, stream>>>(ids, tok_emb, pos_emb, eg, eb, x_f, x_b);

  for (int l = 0; l < 12; ++l) {
    transpose_all_k<<<1728, 256, 0, stream>>>(
        Wqkv + (size_t)l * 768 * 2304, Wo + (size_t)l * 768 * 768,
        W1 + (size_t)l * 768 * 3072, W2 + (size_t)l * 3072 * 768,
        wqkvT, woT, w1T, w2T);

    gemm_bt<128, 0><<<dim3(18, 32), 256, 0, stream>>>(
        x_b, wqkvT, bqkv + (size_t)l * 2304, nullptr, qkv, 4096, 2304, 768);
    attn_k<<<dim3(8, 12, 8), 256, 0, stream>>>(qkv, am, attn);

    // O-proj: split-K4 (Klen=192), partials in dead slabs (qkv consumed by attn)
    gemm_sk<<<dim3(6, 32, 4), 256, 0, stream>>>(
        attn, woT, pp0, pp1, pp2, pp3, 4096, 768, 768, 192);
    ln2_k<<<4096, 256, 0, stream>>>(
        pp0, pp1, pp2, pp3, bo + (size_t)l * 768, x_f,
        g1 + (size_t)l * 768, b1n + (size_t)l * 768, x2_f, x2_b);

    gemm_bt<128, 1><<<dim3(24, 32), 256, 0, stream>>>(
        x2_b, w1T, b1f + (size_t)l * 3072, nullptr, hb, 4096, 3072, 768);

    // FFN2: split-K4 (Klen=768); hb is read-only input, qkv slab dead
    gemm_sk<<<dim3(6, 32, 4), 256, 0, stream>>>(
        hb, w2T, pp0, pp1, pp2, pp3, 4096, 768, 3072, 768);
    ln2_k<<<4096, 256, 0, stream>>>(
        pp0, pp1, pp2, pp3, b2f + (size_t)l * 768, x2_f,
        g2 + (size_t)l * 768, b2n + (size_t)l * 768, x_f, x_b);
  }

  gather_k<<<8, 512, 0, stream>>>(ids, x_f, (float*)d_out);
}